// Round 1
// baseline (1582.265 us; speedup 1.0000x reference)
//
#include <hip/hip_runtime.h>

#define DD 64

// ---------------- edge kernel: g[dst] += norm[src] * h[src] ----------------
__global__ void edge_scatter_kernel(const float* __restrict__ ue,
                                    const float* __restrict__ ie,
                                    const float* __restrict__ norm,
                                    const int* __restrict__ src,
                                    const int* __restrict__ dst,
                                    float* __restrict__ g,
                                    int E, int NU) {
  long long tid = (long long)blockIdx.x * blockDim.x + threadIdx.x;
  long long total = (long long)E * 16;
  if (tid >= total) return;
  int e = (int)(tid >> 4);
  int q = (int)(tid & 15);
  int s = src[e];
  int d = dst[e];
  float ns = norm[s];
  const float* hs = (s < NU) ? (ue + (size_t)s * DD) : (ie + (size_t)(s - NU) * DD);
  float4 hv = *reinterpret_cast<const float4*>(hs + q * 4);
  float* gd = g + (size_t)d * DD + q * 4;
  atomicAdd(gd + 0, ns * hv.x);
  atomicAdd(gd + 1, ns * hv.y);
  atomicAdd(gd + 2, ns * hv.z);
  atomicAdd(gd + 3, ns * hv.w);
}

// ---------------- node kernel: m = (nd*g + h)@W1^T + (nd*(g.*h))@W2^T, LeakyReLU ----------------
__launch_bounds__(256)
__global__ void node_kernel(const float* __restrict__ ue,
                            const float* __restrict__ ie,
                            const float* __restrict__ norm,
                            const float* __restrict__ W1,
                            const float* __restrict__ W2,
                            const float* __restrict__ g,
                            float* __restrict__ out,
                            int Nn, int NU) {
  __shared__ float w1s[DD * DD];
  __shared__ float w2s[DD * DD];
  for (int i = threadIdx.x; i < DD * DD; i += blockDim.x) {
    w1s[i] = W1[i];
    w2s[i] = W2[i];
  }
  __syncthreads();
  int d = blockIdx.x * blockDim.x + threadIdx.x;
  if (d >= Nn) return;
  const float* hrow = (d < NU) ? (ue + (size_t)d * DD) : (ie + (size_t)(d - NU) * DD);
  float nd = norm[d];
  float x[DD], y[DD];
#pragma unroll
  for (int k = 0; k < DD; k += 4) {
    float4 gv = *reinterpret_cast<const float4*>(g + (size_t)d * DD + k);
    float4 hv = *reinterpret_cast<const float4*>(hrow + k);
    x[k + 0] = fmaf(nd, gv.x, hv.x);  y[k + 0] = nd * gv.x * hv.x;
    x[k + 1] = fmaf(nd, gv.y, hv.y);  y[k + 1] = nd * gv.y * hv.y;
    x[k + 2] = fmaf(nd, gv.z, hv.z);  y[k + 2] = nd * gv.z * hv.z;
    x[k + 3] = fmaf(nd, gv.w, hv.w);  y[k + 3] = nd * gv.w * hv.w;
  }
  for (int j = 0; j < DD; ++j) {
    float acc = 0.f;
#pragma unroll
    for (int k = 0; k < DD; ++k) {
      acc = fmaf(x[k], w1s[j * DD + k], acc);
      acc = fmaf(y[k], w2s[j * DD + k], acc);
    }
    out[(size_t)d * DD + j] = (acc >= 0.f) ? acc : 0.2f * acc;
  }
}

// ---------------- row L2 normalize, in place ----------------
__global__ void normalize_kernel(float* __restrict__ out, int Nn) {
  int gtid = blockIdx.x * blockDim.x + threadIdx.x;
  int row = gtid >> 6;
  int lane = gtid & 63;
  if (row >= Nn) return;
  float v = out[(size_t)row * DD + lane];
  float ss = v * v;
#pragma unroll
  for (int off = 32; off; off >>= 1) ss += __shfl_xor(ss, off);
  float s = sqrtf(ss);
  float inv = 1.0f / fmaxf(s, 1e-12f);
  out[(size_t)row * DD + lane] = v * inv;
}

extern "C" void kernel_launch(void* const* d_in, const int* in_sizes, int n_in,
                              void* d_out, int out_size, void* d_ws, size_t ws_size,
                              hipStream_t stream) {
  const float* ue   = (const float*)d_in[0];
  const float* ie   = (const float*)d_in[1];
  const float* norm = (const float*)d_in[2];
  const int*   src  = (const int*)d_in[3];
  const int*   dst  = (const int*)d_in[4];
  const float* W1   = (const float*)d_in[5];
  const float* W2   = (const float*)d_in[6];
  float* out = (float*)d_out;

  int NU = in_sizes[0] / DD;
  int Nn = in_sizes[2];        // norm has N elements
  int E  = in_sizes[3];

  size_t gbytes = (size_t)Nn * DD * sizeof(float);
  // g accumulator: prefer workspace; fall back to accumulating in d_out
  // (safe: node_kernel thread d reads row d fully before writing row d).
  float* g = (ws_size >= gbytes) ? (float*)d_ws : out;

  hipMemsetAsync(g, 0, gbytes, stream);

  long long tot = (long long)E * 16;
  int eblocks = (int)((tot + 255) / 256);
  edge_scatter_kernel<<<eblocks, 256, 0, stream>>>(ue, ie, norm, src, dst, g, E, NU);

  int nblocks = (Nn + 255) / 256;
  node_kernel<<<nblocks, 256, 0, stream>>>(ue, ie, norm, W1, W2, g, out, Nn, NU);

  int zblocks = ((Nn * DD) + 255) / 256;
  normalize_kernel<<<zblocks, 256, 0, stream>>>(out, Nn);
}

// Round 2
// 943.241 us; speedup vs baseline: 1.6775x; 1.6775x over previous
//
#include <hip/hip_runtime.h>

#define DD 64

// =====================  CSR-based fast path  =====================

__global__ void hist_kernel(const int* __restrict__ dst, int* __restrict__ cnt, int E) {
  int e = blockIdx.x * blockDim.x + threadIdx.x;
  if (e < E) atomicAdd(&cnt[dst[e]], 1);
}

// scanA: per-block (4096 elems) exclusive scan of cnt -> offs, block totals -> bsum
__global__ void scanA_kernel(const int* __restrict__ cnt, int* __restrict__ offs,
                             int* __restrict__ bsum, int Nn) {
  __shared__ int wsum[4];
  int base = blockIdx.x * 4096 + threadIdx.x * 16;
  int v[16];
  int s = 0;
#pragma unroll
  for (int i = 0; i < 16; ++i) {
    int idx = base + i;
    v[i] = (idx < Nn) ? cnt[idx] : 0;
    s += v[i];
  }
  int lane = threadIdx.x & 63, w = threadIdx.x >> 6;
  int ps = s;
#pragma unroll
  for (int off = 1; off < 64; off <<= 1) {
    int t = __shfl_up(ps, off);
    if (lane >= off) ps += t;
  }
  if (lane == 63) wsum[w] = ps;
  __syncthreads();
  int wbase = 0;
  for (int i = 0; i < w; ++i) wbase += wsum[i];
  int texcl = wbase + ps - s;  // exclusive base of this thread within block
  int run = texcl;
#pragma unroll
  for (int i = 0; i < 16; ++i) {
    int idx = base + i;
    if (idx < Nn) offs[idx] = run;
    run += v[i];
  }
  if (threadIdx.x == blockDim.x - 1) bsum[blockIdx.x] = texcl + s;
}

__global__ void scanB_kernel(int* __restrict__ bsum, int nb) {
  if (threadIdx.x == 0 && blockIdx.x == 0) {
    int run = 0;
    for (int i = 0; i < nb; ++i) { int t = bsum[i]; bsum[i] = run; run += t; }
  }
}

__global__ void scanC_kernel(int* __restrict__ offs, int* __restrict__ cursor,
                             const int* __restrict__ bsum, int Nn) {
  int i = blockIdx.x * blockDim.x + threadIdx.x;
  if (i < Nn) {
    int v = offs[i] + bsum[i >> 12];
    offs[i] = v;
    cursor[i] = v;
  }
}

__global__ void bucket_kernel(const int* __restrict__ src, const int* __restrict__ dst,
                              int* __restrict__ cursor, int* __restrict__ ebuf, int E) {
  int e = blockIdx.x * blockDim.x + threadIdx.x;
  if (e < E) {
    int d = dst[e];
    int p = atomicAdd(&cursor[d], 1);
    ebuf[p] = src[e];
  }
}

// fused: per-dst gather-sum + (x@W1^T + y@W2^T) + LeakyReLU + L2-normalize
__launch_bounds__(256)
__global__ void fused_gather_kernel(const float* __restrict__ ue,
                                    const float* __restrict__ ie,
                                    const float* __restrict__ norm,
                                    const float* __restrict__ W1,
                                    const float* __restrict__ W2,
                                    const int* __restrict__ offs,
                                    const int* __restrict__ cnt,
                                    const int* __restrict__ ebuf,
                                    float* __restrict__ out,
                                    int Nn, int NU) {
  // transposed + rotate-swizzled weights: w1t[k*64 + ((j+k)&63)] = W1[j*64+k]
  __shared__ float w1t[DD * DD];
  __shared__ float w2t[DD * DD];
  for (int i = threadIdx.x; i < DD * DD; i += blockDim.x) {
    int j = i >> 6, k = i & 63;
    int c = (j + k) & 63;
    w1t[k * DD + c] = W1[i];
    w2t[k * DD + c] = W2[i];
  }
  __syncthreads();

  int lane = threadIdx.x & 63;
  int wid = blockIdx.x * (blockDim.x >> 6) + (threadIdx.x >> 6);
  int nwaves = gridDim.x * (blockDim.x >> 6);

  for (int d = wid; d < Nn; d += nwaves) {
    int beg = offs[d];
    int num = cnt[d];
    float acc = 0.f;
    for (int i0 = 0; i0 < num; i0 += 16) {
      int rem = num - i0;
      int li = lane & 15;
      if (li > rem - 1) li = rem - 1;
      int sv = ebuf[beg + i0 + li];
#pragma unroll
      for (int i = 0; i < 16; ++i) {
        int s = __shfl(sv, i);
        float wgt = norm[s];
        if (i >= rem) wgt = 0.f;
        const float* hr = (s < NU) ? (ue + (size_t)s * DD) : (ie + (size_t)(s - NU) * DD);
        acc = fmaf(wgt, hr[lane], acc);
      }
    }
    // acc = g[d][lane]
    const float* hdr = (d < NU) ? (ue + (size_t)d * DD) : (ie + (size_t)(d - NU) * DD);
    float h = hdr[lane];
    float nd = norm[d];
    float x = fmaf(nd, acc, h);      // nd*g + h
    float y = nd * acc * h;          // nd*(g.*h)
    float m = 0.f;
#pragma unroll
    for (int k = 0; k < DD; ++k) {
      float xk = __shfl(x, k);
      float yk = __shfl(y, k);
      int c = (lane + k) & 63;
      m = fmaf(xk, w1t[k * DD + c], m);
      m = fmaf(yk, w2t[k * DD + c], m);
    }
    float v = (m >= 0.f) ? m : 0.2f * m;
    float ss = v * v;
#pragma unroll
    for (int off = 32; off; off >>= 1) ss += __shfl_xor(ss, off);
    float inv = 1.0f / fmaxf(sqrtf(ss), 1e-12f);
    out[(size_t)d * DD + lane] = v * inv;
  }
}

// =====================  fallback (round-1 atomic path)  =====================

__global__ void edge_scatter_kernel(const float* __restrict__ ue,
                                    const float* __restrict__ ie,
                                    const float* __restrict__ norm,
                                    const int* __restrict__ src,
                                    const int* __restrict__ dst,
                                    float* __restrict__ g,
                                    int E, int NU) {
  long long tid = (long long)blockIdx.x * blockDim.x + threadIdx.x;
  long long total = (long long)E * 16;
  if (tid >= total) return;
  int e = (int)(tid >> 4);
  int q = (int)(tid & 15);
  int s = src[e];
  int d = dst[e];
  float ns = norm[s];
  const float* hs = (s < NU) ? (ue + (size_t)s * DD) : (ie + (size_t)(s - NU) * DD);
  float4 hv = *reinterpret_cast<const float4*>(hs + q * 4);
  float* gd = g + (size_t)d * DD + q * 4;
  atomicAdd(gd + 0, ns * hv.x);
  atomicAdd(gd + 1, ns * hv.y);
  atomicAdd(gd + 2, ns * hv.z);
  atomicAdd(gd + 3, ns * hv.w);
}

__launch_bounds__(256)
__global__ void node_kernel(const float* __restrict__ ue,
                            const float* __restrict__ ie,
                            const float* __restrict__ norm,
                            const float* __restrict__ W1,
                            const float* __restrict__ W2,
                            const float* __restrict__ g,
                            float* __restrict__ out,
                            int Nn, int NU) {
  __shared__ float w1s[DD * DD];
  __shared__ float w2s[DD * DD];
  for (int i = threadIdx.x; i < DD * DD; i += blockDim.x) {
    w1s[i] = W1[i];
    w2s[i] = W2[i];
  }
  __syncthreads();
  int d = blockIdx.x * blockDim.x + threadIdx.x;
  if (d >= Nn) return;
  const float* hrow = (d < NU) ? (ue + (size_t)d * DD) : (ie + (size_t)(d - NU) * DD);
  float nd = norm[d];
  float x[DD], y[DD];
#pragma unroll
  for (int k = 0; k < DD; k += 4) {
    float4 gv = *reinterpret_cast<const float4*>(g + (size_t)d * DD + k);
    float4 hv = *reinterpret_cast<const float4*>(hrow + k);
    x[k + 0] = fmaf(nd, gv.x, hv.x);  y[k + 0] = nd * gv.x * hv.x;
    x[k + 1] = fmaf(nd, gv.y, hv.y);  y[k + 1] = nd * gv.y * hv.y;
    x[k + 2] = fmaf(nd, gv.z, hv.z);  y[k + 2] = nd * gv.z * hv.z;
    x[k + 3] = fmaf(nd, gv.w, hv.w);  y[k + 3] = nd * gv.w * hv.w;
  }
  for (int j = 0; j < DD; ++j) {
    float acc = 0.f;
#pragma unroll
    for (int k = 0; k < DD; ++k) {
      acc = fmaf(x[k], w1s[j * DD + k], acc);
      acc = fmaf(y[k], w2s[j * DD + k], acc);
    }
    out[(size_t)d * DD + j] = (acc >= 0.f) ? acc : 0.2f * acc;
  }
}

__global__ void normalize_kernel(float* __restrict__ out, int Nn) {
  int gtid = blockIdx.x * blockDim.x + threadIdx.x;
  int row = gtid >> 6;
  int lane = gtid & 63;
  if (row >= Nn) return;
  float v = out[(size_t)row * DD + lane];
  float ss = v * v;
#pragma unroll
  for (int off = 32; off; off >>= 1) ss += __shfl_xor(ss, off);
  float inv = 1.0f / fmaxf(sqrtf(ss), 1e-12f);
  out[(size_t)row * DD + lane] = v * inv;
}

// =====================  launch  =====================

extern "C" void kernel_launch(void* const* d_in, const int* in_sizes, int n_in,
                              void* d_out, int out_size, void* d_ws, size_t ws_size,
                              hipStream_t stream) {
  const float* ue   = (const float*)d_in[0];
  const float* ie   = (const float*)d_in[1];
  const float* norm = (const float*)d_in[2];
  const int*   src  = (const int*)d_in[3];
  const int*   dst  = (const int*)d_in[4];
  const float* W1   = (const float*)d_in[5];
  const float* W2   = (const float*)d_in[6];
  float* out = (float*)d_out;

  int NU = in_sizes[0] / DD;
  int Nn = in_sizes[2];   // norm has N elements
  int E  = in_sizes[3];

  size_t needed = ((size_t)3 * Nn + 64 + (size_t)E) * sizeof(int);

  if (ws_size >= needed) {
    int* cnt    = (int*)d_ws;
    int* offs   = cnt + Nn;
    int* cursor = offs + Nn;
    int* bsum   = cursor + Nn;
    int* ebuf   = bsum + 64;

    hipMemsetAsync(cnt, 0, (size_t)Nn * sizeof(int), stream);

    int eblk = (E + 255) / 256;
    hist_kernel<<<eblk, 256, 0, stream>>>(dst, cnt, E);

    int nblkA = (Nn + 4095) / 4096;
    scanA_kernel<<<nblkA, 256, 0, stream>>>(cnt, offs, bsum, Nn);
    scanB_kernel<<<1, 64, 0, stream>>>(bsum, nblkA);
    scanC_kernel<<<(Nn + 255) / 256, 256, 0, stream>>>(offs, cursor, bsum, Nn);

    bucket_kernel<<<eblk, 256, 0, stream>>>(src, dst, cursor, ebuf, E);

    int fblocks = 1280;  // 5 blocks/CU (LDS 32KB) x 256 CUs
    fused_gather_kernel<<<fblocks, 256, 0, stream>>>(ue, ie, norm, W1, W2,
                                                     offs, cnt, ebuf, out, Nn, NU);
  } else {
    // fallback: atomic scatter path
    size_t gbytes = (size_t)Nn * DD * sizeof(float);
    float* g = (ws_size >= gbytes) ? (float*)d_ws : out;
    hipMemsetAsync(g, 0, gbytes, stream);
    long long tot = (long long)E * 16;
    int eblocks = (int)((tot + 255) / 256);
    edge_scatter_kernel<<<eblocks, 256, 0, stream>>>(ue, ie, norm, src, dst, g, E, NU);
    int nblocks = (Nn + 255) / 256;
    node_kernel<<<nblocks, 256, 0, stream>>>(ue, ie, norm, W1, W2, g, out, Nn, NU);
    int zblocks = ((Nn * DD) + 255) / 256;
    normalize_kernel<<<zblocks, 256, 0, stream>>>(out, Nn);
  }
}

// Round 3
// 423.274 us; speedup vs baseline: 3.7382x; 2.2284x over previous
//
#include <hip/hip_runtime.h>

#define DD 64

// =====================  CSR build  =====================

__global__ void hist_kernel(const int* __restrict__ dst, int* __restrict__ cnt, int E) {
  int e = blockIdx.x * blockDim.x + threadIdx.x;
  if (e < E) atomicAdd(&cnt[dst[e]], 1);
}

// scanA: per-block (4096 elems) exclusive scan of cnt -> offs, block totals -> bsum
__global__ void scanA_kernel(const int* __restrict__ cnt, int* __restrict__ offs,
                             int* __restrict__ bsum, int Nn) {
  __shared__ int wsum[4];
  int base = blockIdx.x * 4096 + threadIdx.x * 16;
  int v[16];
  int s = 0;
#pragma unroll
  for (int i = 0; i < 16; ++i) {
    int idx = base + i;
    v[i] = (idx < Nn) ? cnt[idx] : 0;
    s += v[i];
  }
  int lane = threadIdx.x & 63, w = threadIdx.x >> 6;
  int ps = s;
#pragma unroll
  for (int off = 1; off < 64; off <<= 1) {
    int t = __shfl_up(ps, off);
    if (lane >= off) ps += t;
  }
  if (lane == 63) wsum[w] = ps;
  __syncthreads();
  int wbase = 0;
  for (int i = 0; i < w; ++i) wbase += wsum[i];
  int texcl = wbase + ps - s;
  int run = texcl;
#pragma unroll
  for (int i = 0; i < 16; ++i) {
    int idx = base + i;
    if (idx < Nn) offs[idx] = run;
    run += v[i];
  }
  if (threadIdx.x == blockDim.x - 1) bsum[blockIdx.x] = texcl + s;
}

__global__ void scanB_kernel(int* __restrict__ bsum, int nb) {
  if (threadIdx.x == 0 && blockIdx.x == 0) {
    int run = 0;
    for (int i = 0; i < nb; ++i) { int t = bsum[i]; bsum[i] = run; run += t; }
  }
}

__global__ void scanC_kernel(int* __restrict__ offs, int* __restrict__ cursor,
                             const int* __restrict__ bsum, int Nn) {
  int i = blockIdx.x * blockDim.x + threadIdx.x;
  if (i < Nn) {
    int v = offs[i] + bsum[i >> 12];
    offs[i] = v;
    cursor[i] = v;
  }
}

__global__ void bucket_kernel(const int* __restrict__ src, const int* __restrict__ dst,
                              int* __restrict__ cursor, int* __restrict__ ebuf, int E) {
  int e = blockIdx.x * blockDim.x + threadIdx.x;
  if (e < E) {
    int d = dst[e];
    int p = atomicAdd(&cursor[d], 1);
    ebuf[p] = src[e];
  }
}

// =====================  gather: g[d] = sum norm[s]*h[s]  =====================
// wave per node; indices + norms via wave-uniform scalar loads; 4 indep chains.
__launch_bounds__(256)
__global__ void gather_g_kernel(const float* __restrict__ ue,
                                const float* __restrict__ ie,
                                const float* __restrict__ norm,
                                const int* __restrict__ offs,
                                const int* __restrict__ cnt,
                                const int* __restrict__ ebuf,
                                float* __restrict__ g,
                                int Nn, int NU) {
  int lane = threadIdx.x & 63;
  int wid = blockIdx.x * (blockDim.x >> 6) + (threadIdx.x >> 6);
  int d = __builtin_amdgcn_readfirstlane(wid);
  if (d >= Nn) return;
  int beg = __builtin_amdgcn_readfirstlane(offs[d]);
  int num = __builtin_amdgcn_readfirstlane(cnt[d]);
  float a0 = 0.f, a1 = 0.f, a2 = 0.f, a3 = 0.f;
  int i = 0;
  for (; i + 4 <= num; i += 4) {
    int s0 = ebuf[beg + i + 0];
    int s1 = ebuf[beg + i + 1];
    int s2 = ebuf[beg + i + 2];
    int s3 = ebuf[beg + i + 3];
    float w0 = norm[s0], w1 = norm[s1], w2 = norm[s2], w3 = norm[s3];
    const float* r0 = (s0 < NU) ? ue + (size_t)s0 * DD : ie + (size_t)(s0 - NU) * DD;
    const float* r1 = (s1 < NU) ? ue + (size_t)s1 * DD : ie + (size_t)(s1 - NU) * DD;
    const float* r2 = (s2 < NU) ? ue + (size_t)s2 * DD : ie + (size_t)(s2 - NU) * DD;
    const float* r3 = (s3 < NU) ? ue + (size_t)s3 * DD : ie + (size_t)(s3 - NU) * DD;
    a0 = fmaf(w0, r0[lane], a0);
    a1 = fmaf(w1, r1[lane], a1);
    a2 = fmaf(w2, r2[lane], a2);
    a3 = fmaf(w3, r3[lane], a3);
  }
  for (; i < num; ++i) {
    int s0 = ebuf[beg + i];
    float w0 = norm[s0];
    const float* r0 = (s0 < NU) ? ue + (size_t)s0 * DD : ie + (size_t)(s0 - NU) * DD;
    a0 = fmaf(w0, r0[lane], a0);
  }
  g[(size_t)d * DD + lane] = (a0 + a1) + (a2 + a3);
}

// =====================  node transform  =====================
// thread per node: m = (nd*g + h)@W1^T + (nd*(g.*h))@W2^T, LeakyReLU.
__launch_bounds__(256)
__global__ void node_transform_kernel(const float* __restrict__ ue,
                                      const float* __restrict__ ie,
                                      const float* __restrict__ norm,
                                      const float* __restrict__ W1,
                                      const float* __restrict__ W2,
                                      const float* __restrict__ g,
                                      float* __restrict__ out,
                                      int Nn, int NU) {
  __shared__ float w1s[DD * DD];
  __shared__ float w2s[DD * DD];
  for (int i = threadIdx.x; i < DD * DD; i += blockDim.x) {
    w1s[i] = W1[i];
    w2s[i] = W2[i];
  }
  __syncthreads();
  int d = blockIdx.x * blockDim.x + threadIdx.x;
  if (d >= Nn) return;
  const float* hrow = (d < NU) ? (ue + (size_t)d * DD) : (ie + (size_t)(d - NU) * DD);
  float nd = norm[d];
  float x[DD], y[DD];
#pragma unroll
  for (int k = 0; k < DD; k += 4) {
    float4 gv = *reinterpret_cast<const float4*>(g + (size_t)d * DD + k);
    float4 hv = *reinterpret_cast<const float4*>(hrow + k);
    x[k + 0] = fmaf(nd, gv.x, hv.x);  y[k + 0] = nd * gv.x * hv.x;
    x[k + 1] = fmaf(nd, gv.y, hv.y);  y[k + 1] = nd * gv.y * hv.y;
    x[k + 2] = fmaf(nd, gv.z, hv.z);  y[k + 2] = nd * gv.z * hv.z;
    x[k + 3] = fmaf(nd, gv.w, hv.w);  y[k + 3] = nd * gv.w * hv.w;
  }
  for (int j = 0; j < DD; ++j) {
    float acc1 = 0.f, acc2 = 0.f;
#pragma unroll
    for (int k = 0; k < DD; k += 4) {
      float4 wa = *reinterpret_cast<const float4*>(&w1s[j * DD + k]);
      float4 wb = *reinterpret_cast<const float4*>(&w2s[j * DD + k]);
      acc1 = fmaf(x[k + 0], wa.x, acc1);  acc2 = fmaf(y[k + 0], wb.x, acc2);
      acc1 = fmaf(x[k + 1], wa.y, acc1);  acc2 = fmaf(y[k + 1], wb.y, acc2);
      acc1 = fmaf(x[k + 2], wa.z, acc1);  acc2 = fmaf(y[k + 2], wb.z, acc2);
      acc1 = fmaf(x[k + 3], wa.w, acc1);  acc2 = fmaf(y[k + 3], wb.w, acc2);
    }
    float m = acc1 + acc2;
    out[(size_t)d * DD + j] = (m >= 0.f) ? m : 0.2f * m;
  }
}

// =====================  row L2 normalize, in place  =====================
__global__ void normalize_kernel(float* __restrict__ out, int Nn) {
  int gtid = blockIdx.x * blockDim.x + threadIdx.x;
  int row = gtid >> 6;
  int lane = gtid & 63;
  if (row >= Nn) return;
  float v = out[(size_t)row * DD + lane];
  float ss = v * v;
#pragma unroll
  for (int off = 32; off; off >>= 1) ss += __shfl_xor(ss, off);
  float inv = 1.0f / fmaxf(sqrtf(ss), 1e-12f);
  out[(size_t)row * DD + lane] = v * inv;
}

// =====================  fallback (atomic path)  =====================

__global__ void edge_scatter_kernel(const float* __restrict__ ue,
                                    const float* __restrict__ ie,
                                    const float* __restrict__ norm,
                                    const int* __restrict__ src,
                                    const int* __restrict__ dst,
                                    float* __restrict__ g,
                                    int E, int NU) {
  long long tid = (long long)blockIdx.x * blockDim.x + threadIdx.x;
  long long total = (long long)E * 16;
  if (tid >= total) return;
  int e = (int)(tid >> 4);
  int q = (int)(tid & 15);
  int s = src[e];
  int d = dst[e];
  float ns = norm[s];
  const float* hs = (s < NU) ? (ue + (size_t)s * DD) : (ie + (size_t)(s - NU) * DD);
  float4 hv = *reinterpret_cast<const float4*>(hs + q * 4);
  float* gd = g + (size_t)d * DD + q * 4;
  atomicAdd(gd + 0, ns * hv.x);
  atomicAdd(gd + 1, ns * hv.y);
  atomicAdd(gd + 2, ns * hv.z);
  atomicAdd(gd + 3, ns * hv.w);
}

// =====================  launch  =====================

extern "C" void kernel_launch(void* const* d_in, const int* in_sizes, int n_in,
                              void* d_out, int out_size, void* d_ws, size_t ws_size,
                              hipStream_t stream) {
  const float* ue   = (const float*)d_in[0];
  const float* ie   = (const float*)d_in[1];
  const float* norm = (const float*)d_in[2];
  const int*   src  = (const int*)d_in[3];
  const int*   dst  = (const int*)d_in[4];
  const float* W1   = (const float*)d_in[5];
  const float* W2   = (const float*)d_in[6];
  float* out = (float*)d_out;

  int NU = in_sizes[0] / DD;
  int Nn = in_sizes[2];   // norm has N elements
  int E  = in_sizes[3];

  size_t csr_ints = (size_t)3 * Nn + 64 + (size_t)E;
  size_t csr_bytes = csr_ints * sizeof(int);
  size_t g_bytes = (size_t)Nn * DD * sizeof(float);

  if (ws_size >= csr_bytes) {
    int* cnt    = (int*)d_ws;
    int* offs   = cnt + Nn;
    int* cursor = offs + Nn;
    int* bsum   = cursor + Nn;
    int* ebuf   = bsum + 64;
    // g: in ws if room, else accumulate via d_out (safe: each node_transform
    // thread only reads its OWN g row before writing its own out row)
    float* g = (ws_size >= csr_bytes + g_bytes) ? (float*)(ebuf + E) : out;

    hipMemsetAsync(cnt, 0, (size_t)Nn * sizeof(int), stream);

    int eblk = (E + 255) / 256;
    hist_kernel<<<eblk, 256, 0, stream>>>(dst, cnt, E);

    int nblkA = (Nn + 4095) / 4096;
    scanA_kernel<<<nblkA, 256, 0, stream>>>(cnt, offs, bsum, Nn);
    scanB_kernel<<<1, 64, 0, stream>>>(bsum, nblkA);
    scanC_kernel<<<(Nn + 255) / 256, 256, 0, stream>>>(offs, cursor, bsum, Nn);

    bucket_kernel<<<eblk, 256, 0, stream>>>(src, dst, cursor, ebuf, E);

    int gblk = (Nn + 3) / 4;  // 4 waves per 256-thread block, wave per node
    gather_g_kernel<<<gblk, 256, 0, stream>>>(ue, ie, norm, offs, cnt, ebuf, g, Nn, NU);

    node_transform_kernel<<<(Nn + 255) / 256, 256, 0, stream>>>(ue, ie, norm, W1, W2,
                                                                g, out, Nn, NU);
  } else {
    float* g = out;
    hipMemsetAsync(g, 0, g_bytes, stream);
    long long tot = (long long)E * 16;
    edge_scatter_kernel<<<(int)((tot + 255) / 256), 256, 0, stream>>>(ue, ie, norm, src,
                                                                      dst, g, E, NU);
    node_transform_kernel<<<(Nn + 255) / 256, 256, 0, stream>>>(ue, ie, norm, W1, W2,
                                                                g, out, Nn, NU);
  }

  normalize_kernel<<<((Nn * DD) + 255) / 256, 256, 0, stream>>>(out, Nn);
}

// Round 4
// 307.258 us; speedup vs baseline: 5.1496x; 1.3776x over previous
//
#include <hip/hip_runtime.h>

#define DD 64

typedef __attribute__((ext_vector_type(8))) short bfrag;
typedef __attribute__((ext_vector_type(4))) float ffrag;

static __device__ __forceinline__ short f2bf(float f) {
  union { float f; unsigned u; } v; v.f = f;
  unsigned r = v.u + 0x7fff + ((v.u >> 16) & 1);  // round-to-nearest-even
  return (short)(r >> 16);
}

// =====================  CSR build  =====================

__global__ void hist_kernel(const int* __restrict__ dst, int* __restrict__ cnt, int E) {
  int e = blockIdx.x * blockDim.x + threadIdx.x;
  if (e < E) atomicAdd(&cnt[dst[e]], 1);
}

__global__ void scanA_kernel(const int* __restrict__ cnt, int* __restrict__ offs,
                             int* __restrict__ bsum, int Nn) {
  __shared__ int wsum[4];
  int base = blockIdx.x * 4096 + threadIdx.x * 16;
  int v[16];
  int s = 0;
#pragma unroll
  for (int i = 0; i < 16; ++i) {
    int idx = base + i;
    v[i] = (idx < Nn) ? cnt[idx] : 0;
    s += v[i];
  }
  int lane = threadIdx.x & 63, w = threadIdx.x >> 6;
  int ps = s;
#pragma unroll
  for (int off = 1; off < 64; off <<= 1) {
    int t = __shfl_up(ps, off);
    if (lane >= off) ps += t;
  }
  if (lane == 63) wsum[w] = ps;
  __syncthreads();
  int wbase = 0;
  for (int i = 0; i < w; ++i) wbase += wsum[i];
  int texcl = wbase + ps - s;
  int run = texcl;
#pragma unroll
  for (int i = 0; i < 16; ++i) {
    int idx = base + i;
    if (idx < Nn) offs[idx] = run;
    run += v[i];
  }
  if (threadIdx.x == blockDim.x - 1) bsum[blockIdx.x] = texcl + s;
}

__global__ void scanB_kernel(int* __restrict__ bsum, int nb) {
  if (threadIdx.x == 0 && blockIdx.x == 0) {
    int run = 0;
    for (int i = 0; i < nb; ++i) { int t = bsum[i]; bsum[i] = run; run += t; }
  }
}

__global__ void scanC_kernel(int* __restrict__ offs, int* __restrict__ cursor,
                             const int* __restrict__ bsum, int Nn) {
  int i = blockIdx.x * blockDim.x + threadIdx.x;
  if (i < Nn) {
    int v = offs[i] + bsum[i >> 12];
    offs[i] = v;
    cursor[i] = v;
  }
}

__global__ void bucket_kernel(const int* __restrict__ src, const int* __restrict__ dst,
                              int* __restrict__ cursor, int* __restrict__ ebuf, int E) {
  int e = blockIdx.x * blockDim.x + threadIdx.x;
  if (e < E) {
    int d = dst[e];
    int p = atomicAdd(&cursor[d], 1);
    ebuf[p] = src[e];
  }
}

// =====================  gather: g[d] = sum norm[s]*h[s]  =====================
__launch_bounds__(256)
__global__ void gather_g_kernel(const float* __restrict__ ue,
                                const float* __restrict__ ie,
                                const float* __restrict__ norm,
                                const int* __restrict__ offs,
                                const int* __restrict__ cnt,
                                const int* __restrict__ ebuf,
                                float* __restrict__ g,
                                int Nn, int NU) {
  int lane = threadIdx.x & 63;
  int wid = blockIdx.x * (blockDim.x >> 6) + (threadIdx.x >> 6);
  int d = __builtin_amdgcn_readfirstlane(wid);
  if (d >= Nn) return;
  int beg = __builtin_amdgcn_readfirstlane(offs[d]);
  int num = __builtin_amdgcn_readfirstlane(cnt[d]);
  float a0 = 0.f, a1 = 0.f, a2 = 0.f, a3 = 0.f;
  int i = 0;
  for (; i + 4 <= num; i += 4) {
    int s0 = ebuf[beg + i + 0];
    int s1 = ebuf[beg + i + 1];
    int s2 = ebuf[beg + i + 2];
    int s3 = ebuf[beg + i + 3];
    float w0 = norm[s0], w1 = norm[s1], w2 = norm[s2], w3 = norm[s3];
    const float* r0 = (s0 < NU) ? ue + (size_t)s0 * DD : ie + (size_t)(s0 - NU) * DD;
    const float* r1 = (s1 < NU) ? ue + (size_t)s1 * DD : ie + (size_t)(s1 - NU) * DD;
    const float* r2 = (s2 < NU) ? ue + (size_t)s2 * DD : ie + (size_t)(s2 - NU) * DD;
    const float* r3 = (s3 < NU) ? ue + (size_t)s3 * DD : ie + (size_t)(s3 - NU) * DD;
    a0 = fmaf(w0, r0[lane], a0);
    a1 = fmaf(w1, r1[lane], a1);
    a2 = fmaf(w2, r2[lane], a2);
    a3 = fmaf(w3, r3[lane], a3);
  }
  for (; i < num; ++i) {
    int s0 = ebuf[beg + i];
    float w0 = norm[s0];
    const float* r0 = (s0 < NU) ? ue + (size_t)s0 * DD : ie + (size_t)(s0 - NU) * DD;
    a0 = fmaf(w0, r0[lane], a0);
  }
  g[(size_t)d * DD + lane] = (a0 + a1) + (a2 + a3);
}

// ============  node transform via MFMA, fused LeakyReLU + L2-normalize  ============
// OUT[n][j] = LReLU( X[n]@W1[j] + Y[n]@W2[j] ), then row-normalized.
// X = nd*g + h, Y = nd*(g.*h). A/B frags: row=lane&15, k = 8*(lane>>4)+i (contig).
// C/D: col = lane&15, row = (lane>>4)*4 + r.
__launch_bounds__(256)
__global__ void node_mfma_kernel(const float* __restrict__ ue,
                                 const float* __restrict__ ie,
                                 const float* __restrict__ norm,
                                 const float* __restrict__ W1,
                                 const float* __restrict__ W2,
                                 const float* __restrict__ g,
                                 float* __restrict__ out,
                                 int Nn, int NU) {
  int lane = threadIdx.x & 63;
  int l15 = lane & 15;
  int lg  = lane >> 4;  // 0..3
  int tile = blockIdx.x * 4 + (threadIdx.x >> 6);  // 16 nodes per tile

  // per-wave register-resident weight fragments (bf16)
  bfrag w1f[2][4], w2f[2][4];
#pragma unroll
  for (int jt = 0; jt < 4; ++jt) {
    int wrow = jt * 16 + l15;
#pragma unroll
    for (int ks = 0; ks < 2; ++ks) {
      int kb = ks * 32 + lg * 8;
      const float* p1 = W1 + wrow * DD + kb;
      const float* p2 = W2 + wrow * DD + kb;
#pragma unroll
      for (int j = 0; j < 8; ++j) {
        w1f[ks][jt][j] = f2bf(p1[j]);
        w2f[ks][jt][j] = f2bf(p2[j]);
      }
    }
  }

  if (tile * 16 >= Nn) return;
  int node = tile * 16 + l15;
  int nclamp = (node < Nn) ? node : (Nn - 1);
  const float* hrow = (nclamp < NU) ? ue + (size_t)nclamp * DD
                                    : ie + (size_t)(nclamp - NU) * DD;
  const float* grow = g + (size_t)nclamp * DD;
  float nd = norm[nclamp];

  ffrag acc[4];
#pragma unroll
  for (int jt = 0; jt < 4; ++jt) acc[jt] = (ffrag){0.f, 0.f, 0.f, 0.f};

#pragma unroll
  for (int ks = 0; ks < 2; ++ks) {
    int kb = ks * 32 + lg * 8;
    bfrag xf, yf;
#pragma unroll
    for (int j = 0; j < 8; ++j) {
      float gv = grow[kb + j];
      float hv = hrow[kb + j];
      xf[j] = f2bf(fmaf(nd, gv, hv));
      yf[j] = f2bf(nd * gv * hv);
    }
#pragma unroll
    for (int jt = 0; jt < 4; ++jt) {
      acc[jt] = __builtin_amdgcn_mfma_f32_16x16x32_bf16(xf, w1f[ks][jt], acc[jt], 0, 0, 0);
      acc[jt] = __builtin_amdgcn_mfma_f32_16x16x32_bf16(yf, w2f[ks][jt], acc[jt], 0, 0, 0);
    }
  }

  // epilogue: LeakyReLU + row L2 normalize + store
  float v[4][4];   // [r][jt]
  float ss[4];
#pragma unroll
  for (int r = 0; r < 4; ++r) {
    float s = 0.f;
#pragma unroll
    for (int jt = 0; jt < 4; ++jt) {
      float m = acc[jt][r];
      float t = (m >= 0.f) ? m : 0.2f * m;
      v[r][jt] = t;
      s = fmaf(t, t, s);
    }
#pragma unroll
    for (int off = 1; off < 16; off <<= 1) s += __shfl_xor(s, off);
    ss[r] = s;
  }
#pragma unroll
  for (int r = 0; r < 4; ++r) {
    int orow = tile * 16 + lg * 4 + r;
    if (orow < Nn) {
      float inv = 1.0f / fmaxf(sqrtf(ss[r]), 1e-12f);
#pragma unroll
      for (int jt = 0; jt < 4; ++jt)
        out[(size_t)orow * DD + jt * 16 + l15] = v[r][jt] * inv;
    }
  }
}

// =====================  fallback path kernels  =====================

__global__ void edge_scatter_kernel(const float* __restrict__ ue,
                                    const float* __restrict__ ie,
                                    const float* __restrict__ norm,
                                    const int* __restrict__ src,
                                    const int* __restrict__ dst,
                                    float* __restrict__ g,
                                    int E, int NU) {
  long long tid = (long long)blockIdx.x * blockDim.x + threadIdx.x;
  long long total = (long long)E * 16;
  if (tid >= total) return;
  int e = (int)(tid >> 4);
  int q = (int)(tid & 15);
  int s = src[e];
  int d = dst[e];
  float ns = norm[s];
  const float* hs = (s < NU) ? (ue + (size_t)s * DD) : (ie + (size_t)(s - NU) * DD);
  float4 hv = *reinterpret_cast<const float4*>(hs + q * 4);
  float* gd = g + (size_t)d * DD + q * 4;
  atomicAdd(gd + 0, ns * hv.x);
  atomicAdd(gd + 1, ns * hv.y);
  atomicAdd(gd + 2, ns * hv.z);
  atomicAdd(gd + 3, ns * hv.w);
}

__launch_bounds__(256)
__global__ void node_transform_kernel(const float* __restrict__ ue,
                                      const float* __restrict__ ie,
                                      const float* __restrict__ norm,
                                      const float* __restrict__ W1,
                                      const float* __restrict__ W2,
                                      const float* __restrict__ g,
                                      float* __restrict__ out,
                                      int Nn, int NU) {
  __shared__ float w1s[DD * DD];
  __shared__ float w2s[DD * DD];
  for (int i = threadIdx.x; i < DD * DD; i += blockDim.x) {
    w1s[i] = W1[i];
    w2s[i] = W2[i];
  }
  __syncthreads();
  int d = blockIdx.x * blockDim.x + threadIdx.x;
  if (d >= Nn) return;
  const float* hrow = (d < NU) ? (ue + (size_t)d * DD) : (ie + (size_t)(d - NU) * DD);
  float nd = norm[d];
  float x[DD], y[DD];
#pragma unroll
  for (int k = 0; k < DD; k += 4) {
    float4 gv = *reinterpret_cast<const float4*>(g + (size_t)d * DD + k);
    float4 hv = *reinterpret_cast<const float4*>(hrow + k);
    x[k + 0] = fmaf(nd, gv.x, hv.x);  y[k + 0] = nd * gv.x * hv.x;
    x[k + 1] = fmaf(nd, gv.y, hv.y);  y[k + 1] = nd * gv.y * hv.y;
    x[k + 2] = fmaf(nd, gv.z, hv.z);  y[k + 2] = nd * gv.z * hv.z;
    x[k + 3] = fmaf(nd, gv.w, hv.w);  y[k + 3] = nd * gv.w * hv.w;
  }
  for (int j = 0; j < DD; ++j) {
    float acc1 = 0.f, acc2 = 0.f;
#pragma unroll
    for (int k = 0; k < DD; k += 4) {
      float4 wa = *reinterpret_cast<const float4*>(&w1s[j * DD + k]);
      float4 wb = *reinterpret_cast<const float4*>(&w2s[j * DD + k]);
      acc1 = fmaf(x[k + 0], wa.x, acc1);  acc2 = fmaf(y[k + 0], wb.x, acc2);
      acc1 = fmaf(x[k + 1], wa.y, acc1);  acc2 = fmaf(y[k + 1], wb.y, acc2);
      acc1 = fmaf(x[k + 2], wa.z, acc1);  acc2 = fmaf(y[k + 2], wb.z, acc2);
      acc1 = fmaf(x[k + 3], wa.w, acc1);  acc2 = fmaf(y[k + 3], wb.w, acc2);
    }
    float m = acc1 + acc2;
    out[(size_t)d * DD + j] = (m >= 0.f) ? m : 0.2f * m;
  }
}

__global__ void normalize_kernel(float* __restrict__ out, int Nn) {
  int gtid = blockIdx.x * blockDim.x + threadIdx.x;
  int row = gtid >> 6;
  int lane = gtid & 63;
  if (row >= Nn) return;
  float v = out[(size_t)row * DD + lane];
  float ss = v * v;
#pragma unroll
  for (int off = 32; off; off >>= 1) ss += __shfl_xor(ss, off);
  float inv = 1.0f / fmaxf(sqrtf(ss), 1e-12f);
  out[(size_t)row * DD + lane] = v * inv;
}

// =====================  launch  =====================

extern "C" void kernel_launch(void* const* d_in, const int* in_sizes, int n_in,
                              void* d_out, int out_size, void* d_ws, size_t ws_size,
                              hipStream_t stream) {
  const float* ue   = (const float*)d_in[0];
  const float* ie   = (const float*)d_in[1];
  const float* norm = (const float*)d_in[2];
  const int*   src  = (const int*)d_in[3];
  const int*   dst  = (const int*)d_in[4];
  const float* W1   = (const float*)d_in[5];
  const float* W2   = (const float*)d_in[6];
  float* out = (float*)d_out;

  int NU = in_sizes[0] / DD;
  int Nn = in_sizes[2];
  int E  = in_sizes[3];

  size_t csr_ints = (size_t)3 * Nn + 64 + (size_t)E;
  size_t csr_bytes = csr_ints * sizeof(int);
  size_t g_bytes = (size_t)Nn * DD * sizeof(float);

  if (ws_size >= csr_bytes) {
    int* cnt    = (int*)d_ws;
    int* offs   = cnt + Nn;
    int* cursor = offs + Nn;
    int* bsum   = cursor + Nn;
    int* ebuf   = bsum + 64;
    // g in ws if room, else use d_out as the accumulator (safe: node_mfma
    // reads its tile's g rows fully before writing those same out rows).
    float* g = (ws_size >= csr_bytes + g_bytes) ? (float*)(ebuf + E) : out;

    hipMemsetAsync(cnt, 0, (size_t)Nn * sizeof(int), stream);

    int eblk = (E + 255) / 256;
    hist_kernel<<<eblk, 256, 0, stream>>>(dst, cnt, E);

    int nblkA = (Nn + 4095) / 4096;
    scanA_kernel<<<nblkA, 256, 0, stream>>>(cnt, offs, bsum, Nn);
    scanB_kernel<<<1, 64, 0, stream>>>(bsum, nblkA);
    scanC_kernel<<<(Nn + 255) / 256, 256, 0, stream>>>(offs, cursor, bsum, Nn);

    bucket_kernel<<<eblk, 256, 0, stream>>>(src, dst, cursor, ebuf, E);

    int gblk = (Nn + 3) / 4;
    gather_g_kernel<<<gblk, 256, 0, stream>>>(ue, ie, norm, offs, cnt, ebuf, g, Nn, NU);

    int ntiles = (Nn + 15) / 16;
    int nblocks = (ntiles + 3) / 4;
    node_mfma_kernel<<<nblocks, 256, 0, stream>>>(ue, ie, norm, W1, W2, g, out, Nn, NU);
  } else {
    float* g = out;
    hipMemsetAsync(g, 0, g_bytes, stream);
    long long tot = (long long)E * 16;
    edge_scatter_kernel<<<(int)((tot + 255) / 256), 256, 0, stream>>>(ue, ie, norm, src,
                                                                      dst, g, E, NU);
    node_transform_kernel<<<(Nn + 255) / 256, 256, 0, stream>>>(ue, ie, norm, W1, W2,
                                                                g, out, Nn, NU);
    normalize_kernel<<<((Nn * DD) + 255) / 256, 256, 0, stream>>>(out, Nn);
  }
}

// Round 5
// 156.283 us; speedup vs baseline: 10.1243x; 1.9660x over previous
//
#include <hip/hip_runtime.h>

#define DD 64

typedef __attribute__((ext_vector_type(8))) short bfrag;
typedef __attribute__((ext_vector_type(4))) float ffrag;

static __device__ __forceinline__ short f2bf(float f) {
  union { float f; unsigned u; } v; v.f = f;
  unsigned r = v.u + 0x7fff + ((v.u >> 16) & 1);  // RNE
  return (short)(r >> 16);
}
static __device__ __forceinline__ float bf2f(unsigned short u) {
  union { unsigned u; float f; } v; v.u = ((unsigned)u) << 16; return v.f;
}

// ================== two-level CSR build (coarse 256-node buckets) ==================

__global__ void chist_kernel(const int* __restrict__ dst, int* __restrict__ ccnt,
                             int E, int NB) {
  __shared__ int ch[512];
  for (int i = threadIdx.x; i < 512; i += 256) ch[i] = 0;
  __syncthreads();
  int ebase = blockIdx.x * 4096;
#pragma unroll
  for (int j = 0; j < 16; ++j) {
    int e = ebase + j * 256 + threadIdx.x;
    if (e < E) atomicAdd(&ch[dst[e] >> 8], 1);
  }
  __syncthreads();
  for (int b = threadIdx.x; b < NB; b += 256) {
    int c = ch[b];
    if (c) atomicAdd(&ccnt[b], c);
  }
}

// single block, 256 threads, scans up to 512 bucket counts
__global__ void cscan_kernel(const int* __restrict__ ccnt, int* __restrict__ cbase,
                             int* __restrict__ ccursor, int NB) {
  __shared__ int wtot[4];
  int t = threadIdx.x;
  int i0 = t * 2, i1 = t * 2 + 1;
  int v0 = (i0 < NB) ? ccnt[i0] : 0;
  int v1 = (i1 < NB) ? ccnt[i1] : 0;
  int s = v0 + v1;
  int lane = t & 63, w = t >> 6;
  int ps = s;
#pragma unroll
  for (int off = 1; off < 64; off <<= 1) {
    int tmp = __shfl_up(ps, off);
    if (lane >= off) ps += tmp;
  }
  if (lane == 63) wtot[w] = ps;
  __syncthreads();
  int wbase = 0;
  for (int k = 0; k < w; ++k) wbase += wtot[k];
  int excl = wbase + ps - s;
  if (i0 < NB) { cbase[i0] = excl;      ccursor[i0] = excl; }
  if (i1 < NB) { cbase[i1] = excl + v0; ccursor[i1] = excl + v0; }
  if (t == 0) {
    int tot = 0;
    for (int k = 0; k < 4; ++k) tot += wtot[k];
    cbase[NB] = tot;
  }
}

// coarse scatter: pack (src<<8)|dst_local into pairb, grouped by coarse bucket
__global__ void cscatter_kernel(const int* __restrict__ src, const int* __restrict__ dst,
                                int* __restrict__ ccursor, unsigned* __restrict__ pairb,
                                int E, int NB) {
  __shared__ int bh[512], bbase[512], brank[512];
  for (int i = threadIdx.x; i < 512; i += 256) { bh[i] = 0; brank[i] = 0; }
  __syncthreads();
  int ebase = blockIdx.x * 4096;
  int se[16], de[16];
#pragma unroll
  for (int j = 0; j < 16; ++j) {
    int e = ebase + j * 256 + threadIdx.x;
    if (e < E) {
      se[j] = src[e];
      de[j] = dst[e];
      atomicAdd(&bh[de[j] >> 8], 1);
    } else {
      se[j] = -1; de[j] = 0;
    }
  }
  __syncthreads();
  for (int b = threadIdx.x; b < NB; b += 256) {
    int c = bh[b];
    bbase[b] = c ? atomicAdd(&ccursor[b], c) : 0;
  }
  __syncthreads();
#pragma unroll
  for (int j = 0; j < 16; ++j) {
    if (se[j] >= 0) {
      int b = de[j] >> 8;
      int r = atomicAdd(&brank[b], 1);
      pairb[bbase[b] + r] = ((unsigned)se[j] << 8) | (unsigned)(de[j] & 255);
    }
  }
}

// fine pass: one block per coarse bucket; produces offs/cnt and dst-grouped ebuf
__global__ void fine_kernel(const unsigned* __restrict__ pairb,
                            const int* __restrict__ cbase,
                            int* __restrict__ offs, int* __restrict__ cnt,
                            int* __restrict__ ebuf, int Nn) {
  __shared__ int fh[256], fcur[256];
  __shared__ int wtot[4];
  int t = threadIdx.x, b = blockIdx.x;
  int nb0 = b << 8;
  int cbeg = cbase[b], cend = cbase[b + 1];
  fh[t] = 0;
  __syncthreads();
  for (int p = cbeg + t; p < cend; p += 256) atomicAdd(&fh[pairb[p] & 255u], 1);
  __syncthreads();
  int val = fh[t];
  int lane = t & 63, w = t >> 6;
  int ps = val;
#pragma unroll
  for (int off = 1; off < 64; off <<= 1) {
    int tmp = __shfl_up(ps, off);
    if (lane >= off) ps += tmp;
  }
  if (lane == 63) wtot[w] = ps;
  __syncthreads();
  int wbase = 0;
  for (int k = 0; k < w; ++k) wbase += wtot[k];
  int excl = wbase + ps - val;
  int node = nb0 + t;
  if (node < Nn) { offs[node] = cbeg + excl; cnt[node] = val; }
  fcur[t] = cbeg + excl;
  __syncthreads();
  for (int p = cbeg + t; p < cend; p += 256) {
    unsigned v = pairb[p];
    int pos = atomicAdd(&fcur[v & 255u], 1);
    ebuf[pos] = (int)(v >> 8);
  }
}

// ================== pre-scale h by norm into bf16 ==================

__global__ void hconv_kernel(const float* __restrict__ ue, const float* __restrict__ ie,
                             const float* __restrict__ norm,
                             unsigned short* __restrict__ hsc, int Nn, int NU) {
  int tid = blockIdx.x * blockDim.x + threadIdx.x;
  if (tid >= Nn * 16) return;
  int row = tid >> 4;
  int q = tid & 15;
  const float* hr = (row < NU) ? ue + (size_t)row * DD : ie + (size_t)(row - NU) * DD;
  float nr = norm[row];
  float4 hv = reinterpret_cast<const float4*>(hr)[q];
  unsigned u0 = (unsigned short)f2bf(nr * hv.x);
  unsigned u1 = (unsigned short)f2bf(nr * hv.y);
  unsigned u2 = (unsigned short)f2bf(nr * hv.z);
  unsigned u3 = (unsigned short)f2bf(nr * hv.w);
  uint2 pk;
  pk.x = u0 | (u1 << 16);
  pk.y = u2 | (u3 << 16);
  *reinterpret_cast<uint2*>(hsc + (size_t)row * DD + q * 4) = pk;
}

// ================== gather: g[d] = sum hsc[s]  (hsc = norm*h in bf16) ==================

__launch_bounds__(256)
__global__ void gather_hsc_kernel(const unsigned short* __restrict__ hsc,
                                  const int* __restrict__ offs,
                                  const int* __restrict__ cnt,
                                  const int* __restrict__ ebuf,
                                  float* __restrict__ g, int Nn) {
  int lane = threadIdx.x & 63;
  int wid = blockIdx.x * 4 + (threadIdx.x >> 6);
  int d = __builtin_amdgcn_readfirstlane(wid);
  if (d >= Nn) return;
  int beg = __builtin_amdgcn_readfirstlane(offs[d]);
  int num = __builtin_amdgcn_readfirstlane(cnt[d]);
  float a0 = 0.f, a1 = 0.f, a2 = 0.f, a3 = 0.f;
  int i = 0;
  for (; i + 4 <= num; i += 4) {
    int s0 = ebuf[beg + i + 0];
    int s1 = ebuf[beg + i + 1];
    int s2 = ebuf[beg + i + 2];
    int s3 = ebuf[beg + i + 3];
    a0 += bf2f(hsc[(size_t)s0 * DD + lane]);
    a1 += bf2f(hsc[(size_t)s1 * DD + lane]);
    a2 += bf2f(hsc[(size_t)s2 * DD + lane]);
    a3 += bf2f(hsc[(size_t)s3 * DD + lane]);
  }
  for (; i < num; ++i) a0 += bf2f(hsc[(size_t)ebuf[beg + i] * DD + lane]);
  g[(size_t)d * DD + lane] = (a0 + a1) + (a2 + a3);
}

// ============  node transform via MFMA, fused LeakyReLU + L2-normalize  ============

__launch_bounds__(256)
__global__ void node_mfma_kernel(const float* __restrict__ ue,
                                 const float* __restrict__ ie,
                                 const float* __restrict__ norm,
                                 const float* __restrict__ W1,
                                 const float* __restrict__ W2,
                                 const float* __restrict__ g,
                                 float* __restrict__ out,
                                 int Nn, int NU) {
  int lane = threadIdx.x & 63;
  int l15 = lane & 15;
  int lg  = lane >> 4;
  int tile = blockIdx.x * 4 + (threadIdx.x >> 6);

  bfrag w1f[2][4], w2f[2][4];
#pragma unroll
  for (int jt = 0; jt < 4; ++jt) {
    int wrow = jt * 16 + l15;
#pragma unroll
    for (int ks = 0; ks < 2; ++ks) {
      int kb = ks * 32 + lg * 8;
      const float* p1 = W1 + wrow * DD + kb;
      const float* p2 = W2 + wrow * DD + kb;
#pragma unroll
      for (int j = 0; j < 8; ++j) {
        w1f[ks][jt][j] = f2bf(p1[j]);
        w2f[ks][jt][j] = f2bf(p2[j]);
      }
    }
  }

  if (tile * 16 >= Nn) return;
  int node = tile * 16 + l15;
  int nclamp = (node < Nn) ? node : (Nn - 1);
  const float* hrow = (nclamp < NU) ? ue + (size_t)nclamp * DD
                                    : ie + (size_t)(nclamp - NU) * DD;
  const float* grow = g + (size_t)nclamp * DD;
  float nd = norm[nclamp];

  ffrag acc[4];
#pragma unroll
  for (int jt = 0; jt < 4; ++jt) acc[jt] = (ffrag){0.f, 0.f, 0.f, 0.f};

#pragma unroll
  for (int ks = 0; ks < 2; ++ks) {
    int kb = ks * 32 + lg * 8;
    bfrag xf, yf;
#pragma unroll
    for (int j = 0; j < 8; ++j) {
      float gv = grow[kb + j];
      float hv = hrow[kb + j];
      xf[j] = f2bf(fmaf(nd, gv, hv));
      yf[j] = f2bf(nd * gv * hv);
    }
#pragma unroll
    for (int jt = 0; jt < 4; ++jt) {
      acc[jt] = __builtin_amdgcn_mfma_f32_16x16x32_bf16(xf, w1f[ks][jt], acc[jt], 0, 0, 0);
      acc[jt] = __builtin_amdgcn_mfma_f32_16x16x32_bf16(yf, w2f[ks][jt], acc[jt], 0, 0, 0);
    }
  }

  float v[4][4];
  float ss[4];
#pragma unroll
  for (int r = 0; r < 4; ++r) {
    float s = 0.f;
#pragma unroll
    for (int jt = 0; jt < 4; ++jt) {
      float m = acc[jt][r];
      float t = (m >= 0.f) ? m : 0.2f * m;
      v[r][jt] = t;
      s = fmaf(t, t, s);
    }
#pragma unroll
    for (int off = 1; off < 16; off <<= 1) s += __shfl_xor(s, off);
    ss[r] = s;
  }
#pragma unroll
  for (int r = 0; r < 4; ++r) {
    int orow = tile * 16 + lg * 4 + r;
    if (orow < Nn) {
      float inv = 1.0f / fmaxf(sqrtf(ss[r]), 1e-12f);
#pragma unroll
      for (int jt = 0; jt < 4; ++jt)
        out[(size_t)orow * DD + jt * 16 + l15] = v[r][jt] * inv;
    }
  }
}

// =====================  fallback CSR path (round-4)  =====================

__global__ void hist_kernel(const int* __restrict__ dst, int* __restrict__ cnt, int E) {
  int e = blockIdx.x * blockDim.x + threadIdx.x;
  if (e < E) atomicAdd(&cnt[dst[e]], 1);
}

__global__ void scanA_kernel(const int* __restrict__ cnt, int* __restrict__ offs,
                             int* __restrict__ bsum, int Nn) {
  __shared__ int wsum[4];
  int base = blockIdx.x * 4096 + threadIdx.x * 16;
  int v[16];
  int s = 0;
#pragma unroll
  for (int i = 0; i < 16; ++i) {
    int idx = base + i;
    v[i] = (idx < Nn) ? cnt[idx] : 0;
    s += v[i];
  }
  int lane = threadIdx.x & 63, w = threadIdx.x >> 6;
  int ps = s;
#pragma unroll
  for (int off = 1; off < 64; off <<= 1) {
    int t = __shfl_up(ps, off);
    if (lane >= off) ps += t;
  }
  if (lane == 63) wsum[w] = ps;
  __syncthreads();
  int wbase = 0;
  for (int i = 0; i < w; ++i) wbase += wsum[i];
  int texcl = wbase + ps - s;
  int run = texcl;
#pragma unroll
  for (int i = 0; i < 16; ++i) {
    int idx = base + i;
    if (idx < Nn) offs[idx] = run;
    run += v[i];
  }
  if (threadIdx.x == blockDim.x - 1) bsum[blockIdx.x] = texcl + s;
}

__global__ void scanB_kernel(int* __restrict__ bsum, int nb) {
  if (threadIdx.x == 0 && blockIdx.x == 0) {
    int run = 0;
    for (int i = 0; i < nb; ++i) { int t = bsum[i]; bsum[i] = run; run += t; }
  }
}

__global__ void scanC_kernel(int* __restrict__ offs, int* __restrict__ cursor,
                             const int* __restrict__ bsum, int Nn) {
  int i = blockIdx.x * blockDim.x + threadIdx.x;
  if (i < Nn) {
    int v = offs[i] + bsum[i >> 12];
    offs[i] = v;
    cursor[i] = v;
  }
}

__global__ void bucket_kernel(const int* __restrict__ src, const int* __restrict__ dst,
                              int* __restrict__ cursor, int* __restrict__ ebuf, int E) {
  int e = blockIdx.x * blockDim.x + threadIdx.x;
  if (e < E) {
    int d = dst[e];
    int p = atomicAdd(&cursor[d], 1);
    ebuf[p] = src[e];
  }
}

__launch_bounds__(256)
__global__ void gather_g_kernel(const float* __restrict__ ue,
                                const float* __restrict__ ie,
                                const float* __restrict__ norm,
                                const int* __restrict__ offs,
                                const int* __restrict__ cnt,
                                const int* __restrict__ ebuf,
                                float* __restrict__ g,
                                int Nn, int NU) {
  int lane = threadIdx.x & 63;
  int wid = blockIdx.x * (blockDim.x >> 6) + (threadIdx.x >> 6);
  int d = __builtin_amdgcn_readfirstlane(wid);
  if (d >= Nn) return;
  int beg = __builtin_amdgcn_readfirstlane(offs[d]);
  int num = __builtin_amdgcn_readfirstlane(cnt[d]);
  float a0 = 0.f, a1 = 0.f, a2 = 0.f, a3 = 0.f;
  int i = 0;
  for (; i + 4 <= num; i += 4) {
    int s0 = ebuf[beg + i + 0];
    int s1 = ebuf[beg + i + 1];
    int s2 = ebuf[beg + i + 2];
    int s3 = ebuf[beg + i + 3];
    float w0 = norm[s0], w1 = norm[s1], w2 = norm[s2], w3 = norm[s3];
    const float* r0 = (s0 < NU) ? ue + (size_t)s0 * DD : ie + (size_t)(s0 - NU) * DD;
    const float* r1 = (s1 < NU) ? ue + (size_t)s1 * DD : ie + (size_t)(s1 - NU) * DD;
    const float* r2 = (s2 < NU) ? ue + (size_t)s2 * DD : ie + (size_t)(s2 - NU) * DD;
    const float* r3 = (s3 < NU) ? ue + (size_t)s3 * DD : ie + (size_t)(s3 - NU) * DD;
    a0 = fmaf(w0, r0[lane], a0);
    a1 = fmaf(w1, r1[lane], a1);
    a2 = fmaf(w2, r2[lane], a2);
    a3 = fmaf(w3, r3[lane], a3);
  }
  for (; i < num; ++i) {
    int s0 = ebuf[beg + i];
    float w0 = norm[s0];
    const float* r0 = (s0 < NU) ? ue + (size_t)s0 * DD : ie + (size_t)(s0 - NU) * DD;
    a0 = fmaf(w0, r0[lane], a0);
  }
  g[(size_t)d * DD + lane] = (a0 + a1) + (a2 + a3);
}

// =====================  launch  =====================

extern "C" void kernel_launch(void* const* d_in, const int* in_sizes, int n_in,
                              void* d_out, int out_size, void* d_ws, size_t ws_size,
                              hipStream_t stream) {
  const float* ue   = (const float*)d_in[0];
  const float* ie   = (const float*)d_in[1];
  const float* norm = (const float*)d_in[2];
  const int*   src  = (const int*)d_in[3];
  const int*   dst  = (const int*)d_in[4];
  const float* W1   = (const float*)d_in[5];
  const float* W2   = (const float*)d_in[6];
  float* out = (float*)d_out;

  int NU = in_sizes[0] / DD;
  int Nn = in_sizes[2];
  int E  = in_sizes[3];

  int NB = (Nn + 255) >> 8;

  // new-path workspace: ctrl(1538) + offs(Nn) + cnt(Nn) + ebuf(E) + union(pairb E / hsc Nn*32) + pad
  size_t un = ((size_t)E > (size_t)Nn * 32) ? (size_t)E : (size_t)Nn * 32;
  size_t new_ints = 1538 + 2 * (size_t)Nn + (size_t)E + un + 4;
  size_t new_bytes = new_ints * sizeof(int);

  size_t csr_ints = (size_t)3 * Nn + 64 + (size_t)E;
  size_t csr_bytes = csr_ints * sizeof(int);

  if (NB <= 512 && ws_size >= new_bytes) {
    int* ccnt    = (int*)d_ws;          // 512
    int* cbase   = ccnt + 512;          // 513
    int* ccursor = cbase + 513;         // 512  (total 1537, pad to 1538)
    int* offs    = ccnt + 1538;
    int* cnt     = offs + Nn;
    int* ebuf    = cnt + Nn;
    uintptr_t up = (uintptr_t)(ebuf + E);
    up = (up + 7) & ~(uintptr_t)7;
    unsigned*       pairb = (unsigned*)up;
    unsigned short* hsc   = (unsigned short*)up;   // aliases pairb (pairb dead first)
    float* g = out;   // safe: node_mfma reads its own g rows before writing them

    hipMemsetAsync(ccnt, 0, 512 * sizeof(int), stream);

    int EB = (E + 4095) / 4096;
    chist_kernel<<<EB, 256, 0, stream>>>(dst, ccnt, E, NB);
    cscan_kernel<<<1, 256, 0, stream>>>(ccnt, cbase, ccursor, NB);
    cscatter_kernel<<<EB, 256, 0, stream>>>(src, dst, ccursor, pairb, E, NB);
    fine_kernel<<<NB, 256, 0, stream>>>(pairb, cbase, offs, cnt, ebuf, Nn);
    // pairb dead from here; hsc overwrites it
    hconv_kernel<<<(Nn * 16 + 255) / 256, 256, 0, stream>>>(ue, ie, norm, hsc, Nn, NU);
    gather_hsc_kernel<<<(Nn + 3) / 4, 256, 0, stream>>>(hsc, offs, cnt, ebuf, g, Nn);

    int ntiles = (Nn + 15) / 16;
    node_mfma_kernel<<<(ntiles + 3) / 4, 256, 0, stream>>>(ue, ie, norm, W1, W2, g, out,
                                                           Nn, NU);
  } else if (ws_size >= csr_bytes) {
    // round-4 fallback
    int* cnt    = (int*)d_ws;
    int* offs   = cnt + Nn;
    int* cursor = offs + Nn;
    int* bsum   = cursor + Nn;
    int* ebuf   = bsum + 64;
    size_t g_bytes = (size_t)Nn * DD * sizeof(float);
    float* g = (ws_size >= csr_bytes + g_bytes) ? (float*)(ebuf + E) : out;

    hipMemsetAsync(cnt, 0, (size_t)Nn * sizeof(int), stream);
    int eblk = (E + 255) / 256;
    hist_kernel<<<eblk, 256, 0, stream>>>(dst, cnt, E);
    int nblkA = (Nn + 4095) / 4096;
    scanA_kernel<<<nblkA, 256, 0, stream>>>(cnt, offs, bsum, Nn);
    scanB_kernel<<<1, 64, 0, stream>>>(bsum, nblkA);
    scanC_kernel<<<(Nn + 255) / 256, 256, 0, stream>>>(offs, cursor, bsum, Nn);
    bucket_kernel<<<eblk, 256, 0, stream>>>(src, dst, cursor, ebuf, E);
    gather_g_kernel<<<(Nn + 3) / 4, 256, 0, stream>>>(ue, ie, norm, offs, cnt, ebuf,
                                                      g, Nn, NU);
    int ntiles = (Nn + 15) / 16;
    node_mfma_kernel<<<(ntiles + 3) / 4, 256, 0, stream>>>(ue, ie, norm, W1, W2, g, out,
                                                           Nn, NU);
  }
}